// Round 1
// baseline (473.063 us; speedup 1.0000x reference)
//
#include <hip/hip_runtime.h>

#define NN 100000
#define EE 1600000
#define NF 256
#define NH 128

typedef unsigned int u32;

// ---------------- utility ----------------
__global__ void k_zero_i32(u32* __restrict__ p, int n) {
  int i = blockIdx.x * blockDim.x + threadIdx.x;
  if (i < n) p[i] = 0u;
}

// ---------------- degree ----------------
__global__ void k_count(const int* __restrict__ col, u32* __restrict__ cnt) {
  int e = blockIdx.x * blockDim.x + threadIdx.x;
  if (e < EE) {
    u32 d = (u32)col[e];
    if (d < NN) atomicAdd(&cnt[d], 1u);
  }
}

__global__ void k_dinv(const u32* __restrict__ cnt, float* __restrict__ dinv) {
  int n = blockIdx.x * blockDim.x + threadIdx.x;
  if (n < NN) dinv[n] = rsqrtf((float)(cnt[n] + 1u));  // +1 self-loop; never zero
}

// ---------------- scan (3-pass, 256/block) ----------------
__global__ void k_scan_a(const u32* __restrict__ cnt, u32* __restrict__ bsum) {
  __shared__ u32 s[256];
  int t = threadIdx.x;
  int i = blockIdx.x * 256 + t;
  u32 v = (i < NN) ? cnt[i] : 0u;
  s[t] = v;
  __syncthreads();
  for (int d = 128; d > 0; d >>= 1) { if (t < d) s[t] += s[t + d]; __syncthreads(); }
  if (t == 0) bsum[blockIdx.x] = s[0];
}

__global__ void k_scan_b(u32* __restrict__ bsum, int nb, u32* __restrict__ off) {
  __shared__ u32 a[512];
  int t = threadIdx.x;
  u32 v = (t < nb) ? bsum[t] : 0u;
  a[t] = v;
  __syncthreads();
  for (int d = 1; d < 512; d <<= 1) {
    u32 x = a[t];
    if (t >= d) x += a[t - d];
    __syncthreads();
    a[t] = x;
    __syncthreads();
  }
  if (t < nb) bsum[t] = a[t] - v;  // exclusive block base
  if (t == 0) off[NN] = EE;
}

__global__ void k_scan_c(const u32* __restrict__ cnt, const u32* __restrict__ bbase,
                         u32* __restrict__ off) {
  __shared__ u32 a[256];
  int t = threadIdx.x;
  int i = blockIdx.x * 256 + t;
  u32 v = (i < NN) ? cnt[i] : 0u;
  a[t] = v;
  __syncthreads();
  for (int d = 1; d < 256; d <<= 1) {
    u32 x = a[t];
    if (t >= d) x += a[t - d];
    __syncthreads();
    a[t] = x;
    __syncthreads();
  }
  if (i < NN) off[i] = bbase[blockIdx.x] + a[t] - v;
}

// ---------------- CSR fill ----------------
__global__ void k_fill(const int* __restrict__ row, const int* __restrict__ col,
                       const u32* __restrict__ off, u32* __restrict__ cursor,
                       int* __restrict__ csr) {
  int e = blockIdx.x * blockDim.x + threadIdx.x;
  if (e < EE) {
    u32 d = (u32)col[e];
    if (d < NN) {
      u32 pos = off[d] + atomicAdd(&cursor[d], 1u);
      if (pos < EE) csr[pos] = row[e];
    }
  }
}

// ---------------- spectral norm: B = W^T W ----------------
__global__ void k_gram(const float* __restrict__ W, float* __restrict__ B,
                       float* __restrict__ M0, float* __restrict__ tr) {
  __shared__ float wi[NF];
  int i = blockIdx.x, j = threadIdx.x;
  for (int k = j; k < NF; k += NH) wi[k] = W[k * NH + i];
  __syncthreads();
  float acc = 0.f;
  for (int k = 0; k < NF; k++) acc += wi[k] * W[k * NH + j];
  B[i * NH + j] = acc;
  M0[i * NH + j] = acc;
  if (i == j) atomicAdd(tr, acc);
}

// M_out = (M_in / tr_in)^2 ; tr_out += trace(M_out)
__global__ void k_sq(const float* __restrict__ Min, float* __restrict__ Mout,
                     const float* __restrict__ tr_in, float* __restrict__ tr_out) {
  __shared__ float ri[NH];
  int i = blockIdx.x, j = threadIdx.x;
  ri[j] = Min[i * NH + j];
  __syncthreads();
  float acc = 0.f;
  for (int k = 0; k < NH; k++) acc += ri[k] * Min[k * NH + j];
  float it = 1.0f / tr_in[0];
  acc *= it * it;
  Mout[i * NH + j] = acc;
  if (i == j) atomicAdd(tr_out, acc);
}

// Rayleigh quotient of B with dominant column of M  -> sig[0] = 1/sigma
__global__ void k_final(const float* __restrict__ M, const float* __restrict__ B,
                        float* __restrict__ sig) {
  __shared__ float u[NH], red[NH];
  __shared__ int idx[NH];
  int t = threadIdx.x;
  red[t] = M[t * NH + t];
  idx[t] = t;
  __syncthreads();
  for (int d = 64; d > 0; d >>= 1) {
    if (t < d && red[t + d] > red[t]) { red[t] = red[t + d]; idx[t] = idx[t + d]; }
    __syncthreads();
  }
  int jm = idx[0];
  __syncthreads();
  u[t] = M[t * NH + jm];
  __syncthreads();
  float acc = 0.f;
  for (int k = 0; k < NH; k++) acc += B[t * NH + k] * u[k];
  red[t] = u[t] * acc;  // u . (B u)
  __syncthreads();
  for (int d = 64; d > 0; d >>= 1) { if (t < d) red[t] += red[t + d]; __syncthreads(); }
  float numer = red[0];
  __syncthreads();
  red[t] = u[t] * u[t];
  __syncthreads();
  for (int d = 64; d > 0; d >>= 1) { if (t < d) red[t] += red[t + d]; __syncthreads(); }
  float denom = red[0];
  if (t == 0) sig[0] = rsqrtf(numer / denom);  // 1/sqrt(lambda1) = 1/sigma
}

// ---------------- GEMM: hs[n] = dinv[n] * (x[n] @ W) ----------------
#define BM 64
#define KT 16
__global__ __launch_bounds__(256) void k_gemm(const float* __restrict__ x,
                                              const float* __restrict__ W,
                                              const float* __restrict__ dinv,
                                              float* __restrict__ hs) {
  __shared__ float xs[BM][KT + 1];
  __shared__ float wsh[KT][NH];
  int tid = threadIdx.x;
  int row0 = blockIdx.x * BM;
  int tx = tid & 31;   // 32 col-groups of 4
  int ty = tid >> 5;   // 8 row-groups of 8
  float acc[8][4] = {};
  for (int k0 = 0; k0 < NF; k0 += KT) {
    {
      int r = tid >> 2;
      int kk = (tid & 3) * 4;
      int gr = row0 + r;
      if (gr < NN) {
        const float4 v = *(const float4*)&x[(long)gr * NF + k0 + kk];
        xs[r][kk] = v.x; xs[r][kk + 1] = v.y; xs[r][kk + 2] = v.z; xs[r][kk + 3] = v.w;
      }
    }
    {
      int r = tid >> 4;
      int c = (tid & 15) * 8;
      const float4 v0 = *(const float4*)&W[(k0 + r) * NH + c];
      const float4 v1 = *(const float4*)&W[(k0 + r) * NH + c + 4];
      *(float4*)&wsh[r][c] = v0;
      *(float4*)&wsh[r][c + 4] = v1;
    }
    __syncthreads();
    for (int kk = 0; kk < KT; kk++) {
      float4 wv = *(const float4*)&wsh[kk][tx * 4];
#pragma unroll
      for (int i = 0; i < 8; i++) {
        float a = xs[ty * 8 + i][kk];
        acc[i][0] += a * wv.x;
        acc[i][1] += a * wv.y;
        acc[i][2] += a * wv.z;
        acc[i][3] += a * wv.w;
      }
    }
    __syncthreads();
  }
  for (int i = 0; i < 8; i++) {
    int r = row0 + ty * 8 + i;
    if (r < NN) {
      float dv = dinv[r];
      float4 o;
      o.x = acc[i][0] * dv; o.y = acc[i][1] * dv; o.z = acc[i][2] * dv; o.w = acc[i][3] * dv;
      *(float4*)&hs[(long)r * NH + tx * 4] = o;
    }
  }
}

// ---------------- gather + epilogue ----------------
__global__ __launch_bounds__(128) void k_gather(const float* __restrict__ hs,
                                                const int* __restrict__ csr,
                                                const u32* __restrict__ off,
                                                const float* __restrict__ dinv,
                                                const float* __restrict__ b,
                                                const float* __restrict__ pa,
                                                const float* __restrict__ sig,
                                                float* __restrict__ out) {
  int n = blockIdx.x;
  int t = threadIdx.x;
  u32 s0 = off[n], s1 = off[n + 1];
  float acc = hs[(long)n * NH + t];  // self-loop term (dinv[n] already folded)
  u32 e = s0;
  for (; e + 4 <= s1; e += 4) {
    int i0 = csr[e], i1 = csr[e + 1], i2 = csr[e + 2], i3 = csr[e + 3];
    float v0 = hs[(long)i0 * NH + t];
    float v1 = hs[(long)i1 * NH + t];
    float v2 = hs[(long)i2 * NH + t];
    float v3 = hs[(long)i3 * NH + t];
    acc += v0 + v1 + v2 + v3;
  }
  for (; e < s1; e++) acc += hs[(long)csr[e] * NH + t];
  float v = acc * dinv[n] * sig[0] + b[t];
  float a = pa[0];
  out[(long)n * NH + t] = v > 0.f ? v : a * v;
}

// ---------------- launch ----------------
extern "C" void kernel_launch(void* const* d_in, const int* in_sizes, int n_in,
                              void* d_out, int out_size, void* d_ws, size_t ws_size,
                              hipStream_t stream) {
  const float* x = (const float*)d_in[0];
  const int* ei = (const int*)d_in[1];
  const float* W = (const float*)d_in[2];
  const float* b = (const float*)d_in[3];
  const float* pa = (const float*)d_in[4];
  float* out = (float*)d_out;
  const int* row = ei;        // edge_index[0] = sources
  const int* col = ei + EE;   // edge_index[1] = destinations

  char* base = (char*)d_ws;
  size_t o = 0;
  auto alloc = [&](size_t bytes) -> void* {
    void* p = base + o;
    o += (bytes + 63) & ~(size_t)63;
    return p;
  };
  u32* cnt = (u32*)alloc((size_t)NN * 4);
  u32* cursor = (u32*)alloc((size_t)NN * 4);
  float* tr = (float*)alloc(16 * 4);
  float* sig = (float*)alloc(64);
  float* dinv = (float*)alloc((size_t)NN * 4);
  u32* off = (u32*)alloc((size_t)(NN + 4) * 4);
  u32* bsum = (u32*)alloc(512 * 4);
  int* csr = (int*)alloc((size_t)EE * 4);
  float* B = (float*)alloc((size_t)NH * NH * 4);
  float* M0 = (float*)alloc((size_t)NH * NH * 4);
  float* M1 = (float*)alloc((size_t)NH * NH * 4);
  float* hs = (float*)alloc((size_t)NN * NH * 4);
  (void)ws_size; (void)in_sizes; (void)n_in; (void)out_size;

  // zero cnt, cursor, tr, sig (contiguous span up to dinv)
  int zn = (int)(((char*)dinv - (char*)cnt) / 4);
  k_zero_i32<<<(zn + 255) / 256, 256, 0, stream>>>(cnt, zn);

  k_count<<<(EE + 255) / 256, 256, 0, stream>>>(col, cnt);
  k_dinv<<<(NN + 255) / 256, 256, 0, stream>>>(cnt, dinv);

  int nb = (NN + 255) / 256;  // 391
  k_scan_a<<<nb, 256, 0, stream>>>(cnt, bsum);
  k_scan_b<<<1, 512, 0, stream>>>(bsum, nb, off);
  k_scan_c<<<nb, 256, 0, stream>>>(cnt, bsum, off);
  k_fill<<<(EE + 255) / 256, 256, 0, stream>>>(row, col, off, cursor, csr);

  k_gram<<<NH, NH, 0, stream>>>(W, B, M0, tr);
  float* Ms = M0;
  float* Md = M1;
  for (int s = 0; s < 8; s++) {
    k_sq<<<NH, NH, 0, stream>>>(Ms, Md, tr + s, tr + s + 1);
    float* tmp = Ms; Ms = Md; Md = tmp;
  }
  k_final<<<1, NH, 0, stream>>>(Ms, B, sig);

  k_gemm<<<(NN + BM - 1) / BM, 256, 0, stream>>>(x, W, dinv, hs);
  k_gather<<<NN, NH, 0, stream>>>(hs, csr, off, dinv, b, pa, sig, out);
}

// Round 2
// 430.107 us; speedup vs baseline: 1.0999x; 1.0999x over previous
//
#include <hip/hip_runtime.h>

#define NN 100000
#define EE 1600000
#define NF 256
#define NH 128

typedef unsigned int u32;
typedef unsigned short u16;

static __device__ __forceinline__ u16 f2bf(float f) {
  u32 u = __float_as_uint(f);
  u32 r = (u + 0x7FFFu + ((u >> 16) & 1u)) >> 16;
  return (u16)r;
}
static __device__ __forceinline__ float bflo(u32 u) { return __uint_as_float(u << 16); }
static __device__ __forceinline__ float bfhi(u32 u) { return __uint_as_float(u & 0xFFFF0000u); }

// ---------------- degree count ----------------
__global__ void k_count(const int* __restrict__ col, u32* __restrict__ cnt) {
  int e = blockIdx.x * blockDim.x + threadIdx.x;
  if (e < EE) {
    u32 d = (u32)col[e];
    if (d < NN) atomicAdd(&cnt[d], 1u);
  }
}

// ---------------- scan (3-pass) + fused dinv ----------------
__global__ void k_scan_a(const u32* __restrict__ cnt, u32* __restrict__ bsum,
                         float* __restrict__ dinv) {
  __shared__ u32 s[256];
  int t = threadIdx.x;
  int i = blockIdx.x * 256 + t;
  u32 v = (i < NN) ? cnt[i] : 0u;
  if (i < NN) dinv[i] = rsqrtf((float)(v + 1u));  // +1 self-loop
  s[t] = v;
  __syncthreads();
  for (int d = 128; d > 0; d >>= 1) { if (t < d) s[t] += s[t + d]; __syncthreads(); }
  if (t == 0) bsum[blockIdx.x] = s[0];
}

__global__ void k_scan_b(u32* __restrict__ bsum, int nb, u32* __restrict__ off) {
  __shared__ u32 a[512];
  int t = threadIdx.x;
  u32 v = (t < nb) ? bsum[t] : 0u;
  a[t] = v;
  __syncthreads();
  for (int d = 1; d < 512; d <<= 1) {
    u32 x = a[t];
    if (t >= d) x += a[t - d];
    __syncthreads();
    a[t] = x;
    __syncthreads();
  }
  if (t < nb) bsum[t] = a[t] - v;
  if (t == 0) off[NN] = EE;
}

__global__ void k_scan_c(const u32* __restrict__ cnt, const u32* __restrict__ bbase,
                         u32* __restrict__ off) {
  __shared__ u32 a[256];
  int t = threadIdx.x;
  int i = blockIdx.x * 256 + t;
  u32 v = (i < NN) ? cnt[i] : 0u;
  a[t] = v;
  __syncthreads();
  for (int d = 1; d < 256; d <<= 1) {
    u32 x = a[t];
    if (t >= d) x += a[t - d];
    __syncthreads();
    a[t] = x;
    __syncthreads();
  }
  if (i < NN) off[i] = bbase[blockIdx.x] + a[t] - v;
}

// ---------------- CSR fill ----------------
__global__ void k_fill(const int* __restrict__ row, const int* __restrict__ col,
                       const u32* __restrict__ off, u32* __restrict__ cursor,
                       int* __restrict__ csr) {
  int e = blockIdx.x * blockDim.x + threadIdx.x;
  if (e < EE) {
    u32 d = (u32)col[e];
    if (d < NN) {
      u32 pos = off[d] + atomicAdd(&cursor[d], 1u);
      if (pos < EE) csr[pos] = row[e];
    }
  }
}

// ---------------- spectral norm chain (validated in R1) ----------------
__global__ void k_gram(const float* __restrict__ W, float* __restrict__ B,
                       float* __restrict__ M0, float* __restrict__ tr) {
  __shared__ float wi[NF];
  int i = blockIdx.x, j = threadIdx.x;
  for (int k = j; k < NF; k += NH) wi[k] = W[k * NH + i];
  __syncthreads();
  float acc = 0.f;
  for (int k = 0; k < NF; k++) acc += wi[k] * W[k * NH + j];
  B[i * NH + j] = acc;
  M0[i * NH + j] = acc;
  if (i == j) atomicAdd(tr, acc);
}

__global__ void k_sq(const float* __restrict__ Min, float* __restrict__ Mout,
                     const float* __restrict__ tr_in, float* __restrict__ tr_out) {
  __shared__ float ri[NH];
  int i = blockIdx.x, j = threadIdx.x;
  ri[j] = Min[i * NH + j];
  __syncthreads();
  float acc = 0.f;
  for (int k = 0; k < NH; k++) acc += ri[k] * Min[k * NH + j];
  float it = 1.0f / tr_in[0];
  acc *= it * it;
  Mout[i * NH + j] = acc;
  if (i == j) atomicAdd(tr_out, acc);
}

__global__ void k_final(const float* __restrict__ M, const float* __restrict__ B,
                        float* __restrict__ sig) {
  __shared__ float u[NH], red[NH];
  __shared__ int idx[NH];
  int t = threadIdx.x;
  red[t] = M[t * NH + t];
  idx[t] = t;
  __syncthreads();
  for (int d = 64; d > 0; d >>= 1) {
    if (t < d && red[t + d] > red[t]) { red[t] = red[t + d]; idx[t] = idx[t + d]; }
    __syncthreads();
  }
  int jm = idx[0];
  __syncthreads();
  u[t] = M[t * NH + jm];
  __syncthreads();
  float acc = 0.f;
  for (int k = 0; k < NH; k++) acc += B[t * NH + k] * u[k];
  red[t] = u[t] * acc;
  __syncthreads();
  for (int d = 64; d > 0; d >>= 1) { if (t < d) red[t] += red[t + d]; __syncthreads(); }
  float numer = red[0];
  __syncthreads();
  red[t] = u[t] * u[t];
  __syncthreads();
  for (int d = 64; d > 0; d >>= 1) { if (t < d) red[t] += red[t + d]; __syncthreads(); }
  float denom = red[0];
  if (t == 0) sig[0] = rsqrtf(numer / denom);  // 1/sigma
}

// ---------------- GEMM: hs_bf16[n] = bf16(dinv[n] * (x[n] @ W)) ----------------
#define GBM 128
#define GKT 16
__global__ __launch_bounds__(256) void k_gemm(const float* __restrict__ x,
                                              const float* __restrict__ W,
                                              const float* __restrict__ dinv,
                                              u16* __restrict__ hs) {
  __shared__ float xsT[GKT][GBM + 4];  // transposed x tile
  __shared__ float wsh[GKT][NH + 4];
  int tid = threadIdx.x;
  int tx = tid & 15;   // col group: cols tx*8 .. +7
  int ty = tid >> 4;   // row group: rows ty*8 .. +7
  int row0 = blockIdx.x * GBM;

  int sr = tid >> 1;            // x-stage row 0..127
  int sk = (tid & 1) * 8;       // x-stage k offset 0/8
  int wr = tid >> 4;            // W-stage k 0..15
  int wc = (tid & 15) * 8;      // W-stage col
  int gr = row0 + sr;
  long xrow = (long)((gr < NN) ? gr : (NN - 1)) * NF;

  float acc[8][8] = {};
  for (int k0 = 0; k0 < NF; k0 += GKT) {
    float4 a0 = *(const float4*)&x[xrow + k0 + sk];
    float4 a1 = *(const float4*)&x[xrow + k0 + sk + 4];
    float4 w0 = *(const float4*)&W[(k0 + wr) * NH + wc];
    float4 w1 = *(const float4*)&W[(k0 + wr) * NH + wc + 4];
    __syncthreads();
    xsT[sk + 0][sr] = a0.x; xsT[sk + 1][sr] = a0.y;
    xsT[sk + 2][sr] = a0.z; xsT[sk + 3][sr] = a0.w;
    xsT[sk + 4][sr] = a1.x; xsT[sk + 5][sr] = a1.y;
    xsT[sk + 6][sr] = a1.z; xsT[sk + 7][sr] = a1.w;
    *(float4*)&wsh[wr][wc] = w0;
    *(float4*)&wsh[wr][wc + 4] = w1;
    __syncthreads();
#pragma unroll
    for (int kk = 0; kk < GKT; kk++) {
      float av[8], bv[8];
      *(float4*)&av[0] = *(const float4*)&xsT[kk][ty * 8];
      *(float4*)&av[4] = *(const float4*)&xsT[kk][ty * 8 + 4];
      *(float4*)&bv[0] = *(const float4*)&wsh[kk][tx * 8];
      *(float4*)&bv[4] = *(const float4*)&wsh[kk][tx * 8 + 4];
#pragma unroll
      for (int i = 0; i < 8; i++)
#pragma unroll
        for (int j = 0; j < 8; j++) acc[i][j] += av[i] * bv[j];
    }
  }
#pragma unroll
  for (int i = 0; i < 8; i++) {
    int r = row0 + ty * 8 + i;
    if (r < NN) {
      float dv = dinv[r];
      u32 o[4];
#pragma unroll
      for (int j2 = 0; j2 < 4; j2++) {
        u32 lo = f2bf(acc[i][2 * j2] * dv);
        u32 hi = f2bf(acc[i][2 * j2 + 1] * dv);
        o[j2] = lo | (hi << 16);
      }
      *(uint4*)&hs[(size_t)r * NH + tx * 8] = *(uint4*)o;
    }
  }
}

// ---------------- gather + epilogue (wave per node, bf16 rows) ----------------
__global__ __launch_bounds__(256) void k_gather(const u16* __restrict__ hs,
                                                const int* __restrict__ csr,
                                                const u32* __restrict__ off,
                                                const float* __restrict__ dinv,
                                                const float* __restrict__ b,
                                                const float* __restrict__ pa,
                                                const float* __restrict__ sig,
                                                float* __restrict__ out) {
  int wid = threadIdx.x >> 6;
  int lane = threadIdx.x & 63;
  int n = blockIdx.x * 4 + wid;
  if (n >= NN) return;
  u32 s0 = off[n], s1 = off[n + 1];
  const u32* hrow = (const u32*)hs;  // 2 bf16 per u32; row stride = 64 u32
  float ax, ay;
  {
    u32 u = hrow[(size_t)n * 64 + lane];  // self-loop term
    ax = bflo(u); ay = bfhi(u);
  }
  u32 e = s0;
  for (; e + 4 <= s1; e += 4) {
    int i0 = csr[e], i1 = csr[e + 1], i2 = csr[e + 2], i3 = csr[e + 3];
    u32 u0 = hrow[(size_t)i0 * 64 + lane];
    u32 u1 = hrow[(size_t)i1 * 64 + lane];
    u32 u2 = hrow[(size_t)i2 * 64 + lane];
    u32 u3 = hrow[(size_t)i3 * 64 + lane];
    ax += bflo(u0) + bflo(u1) + bflo(u2) + bflo(u3);
    ay += bfhi(u0) + bfhi(u1) + bfhi(u2) + bfhi(u3);
  }
  for (; e < s1; e++) {
    u32 u = hrow[(size_t)csr[e] * 64 + lane];
    ax += bflo(u); ay += bfhi(u);
  }
  float dv = dinv[n] * sig[0];
  float2 bb = *(const float2*)&b[lane * 2];
  float a = pa[0];
  float v0 = ax * dv + bb.x;
  float v1 = ay * dv + bb.y;
  float2 o;
  o.x = v0 > 0.f ? v0 : a * v0;
  o.y = v1 > 0.f ? v1 : a * v1;
  *(float2*)&out[(size_t)n * NH + lane * 2] = o;
}

// ---------------- launch ----------------
extern "C" void kernel_launch(void* const* d_in, const int* in_sizes, int n_in,
                              void* d_out, int out_size, void* d_ws, size_t ws_size,
                              hipStream_t stream) {
  const float* x = (const float*)d_in[0];
  const int* ei = (const int*)d_in[1];
  const float* W = (const float*)d_in[2];
  const float* b = (const float*)d_in[3];
  const float* pa = (const float*)d_in[4];
  float* out = (float*)d_out;
  const int* row = ei;        // sources
  const int* col = ei + EE;   // destinations

  char* base = (char*)d_ws;
  size_t o = 0;
  auto alloc = [&](size_t bytes) -> void* {
    void* p = base + o;
    o += (bytes + 63) & ~(size_t)63;
    return p;
  };
  u32* cnt = (u32*)alloc((size_t)NN * 4);
  u32* cursor = (u32*)alloc((size_t)NN * 4);
  float* tr = (float*)alloc(16 * 4);
  float* sig = (float*)alloc(64);
  // --- everything above is zeroed each call ---
  size_t zbytes = o;
  float* dinv = (float*)alloc((size_t)NN * 4);
  u32* off = (u32*)alloc((size_t)(NN + 4) * 4);
  u32* bsum = (u32*)alloc(512 * 4);
  int* csr = (int*)alloc((size_t)EE * 4);
  float* B = (float*)alloc((size_t)NH * NH * 4);
  float* M0 = (float*)alloc((size_t)NH * NH * 4);
  float* M1 = (float*)alloc((size_t)NH * NH * 4);
  u16* hs = (u16*)alloc((size_t)NN * NH * 2);
  (void)ws_size; (void)in_sizes; (void)n_in; (void)out_size;

  hipMemsetAsync(cnt, 0, zbytes, stream);

  k_count<<<(EE + 255) / 256, 256, 0, stream>>>(col, cnt);

  int nb = (NN + 255) / 256;  // 391
  k_scan_a<<<nb, 256, 0, stream>>>(cnt, bsum, dinv);
  k_scan_b<<<1, 512, 0, stream>>>(bsum, nb, off);
  k_scan_c<<<nb, 256, 0, stream>>>(cnt, bsum, off);
  k_fill<<<(EE + 255) / 256, 256, 0, stream>>>(row, col, off, cursor, csr);

  k_gram<<<NH, NH, 0, stream>>>(W, B, M0, tr);
  float* Ms = M0;
  float* Md = M1;
  for (int s = 0; s < 8; s++) {
    k_sq<<<NH, NH, 0, stream>>>(Ms, Md, tr + s, tr + s + 1);
    float* tmp = Ms; Ms = Md; Md = tmp;
  }
  k_final<<<1, NH, 0, stream>>>(Ms, B, sig);

  k_gemm<<<(NN + GBM - 1) / GBM, 256, 0, stream>>>(x, W, dinv, hs);
  k_gather<<<(NN + 3) / 4, 256, 0, stream>>>(hs, csr, off, dinv, b, pa, sig, out);
}

// Round 3
// 385.073 us; speedup vs baseline: 1.2285x; 1.1169x over previous
//
#include <hip/hip_runtime.h>

#define NN 100000
#define EE 1600000
#define NF 256
#define NH 128

typedef unsigned int u32;
typedef unsigned short u16;
typedef __attribute__((ext_vector_type(8))) short short8;
typedef __attribute__((ext_vector_type(4))) float f32x4;

static __device__ __forceinline__ u16 f2bf(float f) {
  u32 u = __float_as_uint(f);
  u32 r = (u + 0x7FFFu + ((u >> 16) & 1u)) >> 16;
  return (u16)r;
}
static __device__ __forceinline__ float bflo(u32 u) { return __uint_as_float(u << 16); }
static __device__ __forceinline__ float bfhi(u32 u) { return __uint_as_float(u & 0xFFFF0000u); }

// ---------------- degree count ----------------
__global__ void k_count(const int* __restrict__ col, u32* __restrict__ cnt) {
  int e = blockIdx.x * blockDim.x + threadIdx.x;
  if (e < EE) {
    u32 d = (u32)col[e];
    if (d < NN) atomicAdd(&cnt[d], 1u);
  }
}

// ---------------- scan (3-pass) + fused dinv ----------------
__global__ void k_scan_a(const u32* __restrict__ cnt, u32* __restrict__ bsum,
                         float* __restrict__ dinv) {
  __shared__ u32 s[256];
  int t = threadIdx.x;
  int i = blockIdx.x * 256 + t;
  u32 v = (i < NN) ? cnt[i] : 0u;
  if (i < NN) dinv[i] = rsqrtf((float)(v + 1u));  // +1 self-loop
  s[t] = v;
  __syncthreads();
  for (int d = 128; d > 0; d >>= 1) { if (t < d) s[t] += s[t + d]; __syncthreads(); }
  if (t == 0) bsum[blockIdx.x] = s[0];
}

__global__ void k_scan_b(u32* __restrict__ bsum, int nb, u32* __restrict__ off) {
  __shared__ u32 a[512];
  int t = threadIdx.x;
  u32 v = (t < nb) ? bsum[t] : 0u;
  a[t] = v;
  __syncthreads();
  for (int d = 1; d < 512; d <<= 1) {
    u32 x = a[t];
    if (t >= d) x += a[t - d];
    __syncthreads();
    a[t] = x;
    __syncthreads();
  }
  if (t < nb) bsum[t] = a[t] - v;
  if (t == 0) off[NN] = EE;
}

__global__ void k_scan_c(const u32* __restrict__ cnt, const u32* __restrict__ bbase,
                         u32* __restrict__ off) {
  __shared__ u32 a[256];
  int t = threadIdx.x;
  int i = blockIdx.x * 256 + t;
  u32 v = (i < NN) ? cnt[i] : 0u;
  a[t] = v;
  __syncthreads();
  for (int d = 1; d < 256; d <<= 1) {
    u32 x = a[t];
    if (t >= d) x += a[t - d];
    __syncthreads();
    a[t] = x;
    __syncthreads();
  }
  if (i < NN) off[i] = bbase[blockIdx.x] + a[t] - v;
}

// ---------------- CSR fill ----------------
__global__ void k_fill(const int* __restrict__ row, const int* __restrict__ col,
                       const u32* __restrict__ off, u32* __restrict__ cursor,
                       int* __restrict__ csr) {
  int e = blockIdx.x * blockDim.x + threadIdx.x;
  if (e < EE) {
    u32 d = (u32)col[e];
    if (d < NN) {
      u32 pos = off[d] + atomicAdd(&cursor[d], 1u);
      if (pos < EE) csr[pos] = row[e];
    }
  }
}

// ---------------- W transpose + bf16 convert: Wt[c][k] ----------------
__global__ void k_cvtw(const float* __restrict__ W, u16* __restrict__ Wt) {
  int idx = blockIdx.x * 256 + threadIdx.x;
  if (idx < NF * NH) {
    int c = idx >> 8;   // 0..127
    int k = idx & 255;  // 0..255
    Wt[idx] = f2bf(W[k * NH + c]);
  }
}

// ---------------- spectral norm chain (validated R1/R2) ----------------
__global__ void k_gram(const float* __restrict__ W, float* __restrict__ B,
                       float* __restrict__ M0, float* __restrict__ tr) {
  __shared__ float wi[NF];
  int i = blockIdx.x, j = threadIdx.x;
  for (int k = j; k < NF; k += NH) wi[k] = W[k * NH + i];
  __syncthreads();
  float acc = 0.f;
  for (int k = 0; k < NF; k++) acc += wi[k] * W[k * NH + j];
  B[i * NH + j] = acc;
  M0[i * NH + j] = acc;
  if (i == j) atomicAdd(tr, acc);
}

__global__ void k_sq(const float* __restrict__ Min, float* __restrict__ Mout,
                     const float* __restrict__ tr_in, float* __restrict__ tr_out) {
  __shared__ float ri[NH];
  int i = blockIdx.x, j = threadIdx.x;
  ri[j] = Min[i * NH + j];
  __syncthreads();
  float acc = 0.f;
  for (int k = 0; k < NH; k++) acc += ri[k] * Min[k * NH + j];
  float it = 1.0f / tr_in[0];
  acc *= it * it;
  Mout[i * NH + j] = acc;
  if (i == j) atomicAdd(tr_out, acc);
}

__global__ void k_final(const float* __restrict__ M, const float* __restrict__ B,
                        float* __restrict__ sig) {
  __shared__ float u[NH], red[NH];
  __shared__ int idx[NH];
  int t = threadIdx.x;
  red[t] = M[t * NH + t];
  idx[t] = t;
  __syncthreads();
  for (int d = 64; d > 0; d >>= 1) {
    if (t < d && red[t + d] > red[t]) { red[t] = red[t + d]; idx[t] = idx[t + d]; }
    __syncthreads();
  }
  int jm = idx[0];
  __syncthreads();
  u[t] = M[t * NH + jm];
  __syncthreads();
  float acc = 0.f;
  for (int k = 0; k < NH; k++) acc += B[t * NH + k] * u[k];
  red[t] = u[t] * acc;
  __syncthreads();
  for (int d = 64; d > 0; d >>= 1) { if (t < d) red[t] += red[t + d]; __syncthreads(); }
  float numer = red[0];
  __syncthreads();
  red[t] = u[t] * u[t];
  __syncthreads();
  for (int d = 64; d > 0; d >>= 1) { if (t < d) red[t] += red[t + d]; __syncthreads(); }
  float denom = red[0];
  if (t == 0) sig[0] = rsqrtf(numer / denom);  // 1/sigma
}

// ---------------- MFMA GEMM: hs_bf16[n] = bf16(dinv[n] * (x[n] @ W)) -------
// 128x128 tile, 4 waves (each 32 rows x 128 cols), K-step 64.
// LDS rows are 128B with XOR swizzle inner ^= (row&7)<<4 on write AND read.
__global__ __launch_bounds__(256) void k_mfma(const float* __restrict__ x,
                                              const u16* __restrict__ Wt,
                                              const float* __restrict__ dinv,
                                              u16* __restrict__ hs) {
  __shared__ __align__(16) char As[128 * 128];  // 16KB: A tile, row-major 128B rows
  __shared__ __align__(16) char Bs[128 * 128];  // 16KB: Wt tile (col-major B)
  int t = threadIdx.x;
  int l = t & 63, w = t >> 6;
  int row0 = blockIdx.x * 128;

  int ar = t >> 1;        // A staging row 0..127
  int ah = t & 1;         // k-half (32 floats)
  long agr = (long)((row0 + ar < NN) ? (row0 + ar) : (NN - 1)) * NF;
  int bc = t >> 1;        // B staging col (Wt row)
  int bh = t & 1;

  f32x4 acc[2][8] = {};

  for (int ks = 0; ks < 4; ks++) {
    int k0 = ks * 64;
    // --- issue global loads (overlap previous compute) ---
    float4 av[8];
    uint4 bv[4];
#pragma unroll
    for (int i = 0; i < 8; i++) av[i] = *(const float4*)&x[agr + k0 + ah * 32 + i * 4];
#pragma unroll
    for (int i = 0; i < 4; i++) bv[i] = *(const uint4*)&Wt[bc * 256 + k0 + (bh * 4 + i) * 8];
    __syncthreads();  // previous compute done reading LDS
    // --- stage A (cvt f32->bf16) ---
#pragma unroll
    for (int q = 0; q < 4; q++) {
      const float* f = (const float*)&av[q * 2];
      u32 wd[4];
#pragma unroll
      for (int i2 = 0; i2 < 4; i2++)
        wd[i2] = (u32)f2bf(f[2 * i2]) | ((u32)f2bf(f[2 * i2 + 1]) << 16);
      int inner = (ah * 64 + q * 16) ^ ((ar & 7) << 4);
      *(uint4*)(As + ar * 128 + inner) = *(uint4*)wd;
    }
    // --- stage B ---
#pragma unroll
    for (int i = 0; i < 4; i++) {
      int inner = ((bh * 4 + i) * 16) ^ ((bc & 7) << 4);
      *(uint4*)(Bs + bc * 128 + inner) = bv[i];
    }
    __syncthreads();
    // --- compute: 2 ksub x (2 m-frags x 8 n-frags) ---
#pragma unroll
    for (int ksub = 0; ksub < 2; ksub++) {
      int kin = ksub * 64 + (l >> 4) * 16;
      short8 af[2], bf[8];
#pragma unroll
      for (int m = 0; m < 2; m++) {
        int r = w * 32 + m * 16 + (l & 15);
        af[m] = *(const short8*)(As + r * 128 + (kin ^ ((r & 7) << 4)));
      }
#pragma unroll
      for (int n = 0; n < 8; n++) {
        int c = n * 16 + (l & 15);
        bf[n] = *(const short8*)(Bs + c * 128 + (kin ^ ((c & 7) << 4)));
      }
#pragma unroll
      for (int m = 0; m < 2; m++)
#pragma unroll
        for (int n = 0; n < 8; n++)
          acc[m][n] = __builtin_amdgcn_mfma_f32_16x16x32_bf16(af[m], bf[n], acc[m][n], 0, 0, 0);
    }
  }
  // --- epilogue: C/D layout col=lane&15, row=(lane>>4)*4+reg ---
#pragma unroll
  for (int m = 0; m < 2; m++) {
    int rb = row0 + w * 32 + m * 16 + (l >> 4) * 4;
    float dv[4];
#pragma unroll
    for (int g = 0; g < 4; g++) dv[g] = (rb + g < NN) ? dinv[rb + g] : 0.f;
#pragma unroll
    for (int n = 0; n < 8; n++) {
      int c = n * 16 + (l & 15);
#pragma unroll
      for (int g = 0; g < 4; g++) {
        int r = rb + g;
        if (r < NN) hs[(size_t)r * NH + c] = f2bf(acc[m][n][g] * dv[g]);
      }
    }
  }
}

// ---------------- gather + epilogue (wave per node, bf16 rows) ----------------
__global__ __launch_bounds__(256) void k_gather(const u16* __restrict__ hs,
                                                const int* __restrict__ csr,
                                                const u32* __restrict__ off,
                                                const float* __restrict__ dinv,
                                                const float* __restrict__ b,
                                                const float* __restrict__ pa,
                                                const float* __restrict__ sig,
                                                float* __restrict__ out) {
  int wid = threadIdx.x >> 6;
  int lane = threadIdx.x & 63;
  int n = blockIdx.x * 4 + wid;
  if (n >= NN) return;
  u32 s0 = off[n], s1 = off[n + 1];
  const u32* hrow = (const u32*)hs;  // 2 bf16 per u32; row stride 64 u32
  float ax, ay;
  {
    u32 u = hrow[(size_t)n * 64 + lane];  // self-loop term
    ax = bflo(u); ay = bfhi(u);
  }
  u32 e = s0;
  for (; e + 4 <= s1; e += 4) {
    int i0 = csr[e], i1 = csr[e + 1], i2 = csr[e + 2], i3 = csr[e + 3];
    u32 u0 = hrow[(size_t)i0 * 64 + lane];
    u32 u1 = hrow[(size_t)i1 * 64 + lane];
    u32 u2 = hrow[(size_t)i2 * 64 + lane];
    u32 u3 = hrow[(size_t)i3 * 64 + lane];
    ax += bflo(u0) + bflo(u1) + bflo(u2) + bflo(u3);
    ay += bfhi(u0) + bfhi(u1) + bfhi(u2) + bfhi(u3);
  }
  for (; e < s1; e++) {
    u32 u = hrow[(size_t)csr[e] * 64 + lane];
    ax += bflo(u); ay += bfhi(u);
  }
  float dv = dinv[n] * sig[0];
  float2 bb = *(const float2*)&b[lane * 2];
  float a = pa[0];
  float v0 = ax * dv + bb.x;
  float v1 = ay * dv + bb.y;
  float2 o;
  o.x = v0 > 0.f ? v0 : a * v0;
  o.y = v1 > 0.f ? v1 : a * v1;
  *(float2*)&out[(size_t)n * NH + lane * 2] = o;
}

// ---------------- launch ----------------
extern "C" void kernel_launch(void* const* d_in, const int* in_sizes, int n_in,
                              void* d_out, int out_size, void* d_ws, size_t ws_size,
                              hipStream_t stream) {
  const float* x = (const float*)d_in[0];
  const int* ei = (const int*)d_in[1];
  const float* W = (const float*)d_in[2];
  const float* b = (const float*)d_in[3];
  const float* pa = (const float*)d_in[4];
  float* out = (float*)d_out;
  const int* row = ei;        // sources
  const int* col = ei + EE;   // destinations

  char* base = (char*)d_ws;
  size_t o = 0;
  auto alloc = [&](size_t bytes) -> void* {
    void* p = base + o;
    o += (bytes + 63) & ~(size_t)63;
    return p;
  };
  u32* cnt = (u32*)alloc((size_t)NN * 4);
  u32* cursor = (u32*)alloc((size_t)NN * 4);
  float* tr = (float*)alloc(16 * 4);
  float* sig = (float*)alloc(64);
  // --- everything above zeroed each call ---
  size_t zbytes = o;
  float* dinv = (float*)alloc((size_t)NN * 4);
  u32* off = (u32*)alloc((size_t)(NN + 4) * 4);
  u32* bsum = (u32*)alloc(512 * 4);
  int* csr = (int*)alloc((size_t)EE * 4);
  float* B = (float*)alloc((size_t)NH * NH * 4);
  float* M0 = (float*)alloc((size_t)NH * NH * 4);
  float* M1 = (float*)alloc((size_t)NH * NH * 4);
  u16* Wt = (u16*)alloc((size_t)NF * NH * 2);
  u16* hs = (u16*)alloc((size_t)NN * NH * 2);
  (void)ws_size; (void)in_sizes; (void)n_in; (void)out_size;

  hipMemsetAsync(cnt, 0, zbytes, stream);

  k_count<<<(EE + 255) / 256, 256, 0, stream>>>(col, cnt);

  int nb = (NN + 255) / 256;  // 391
  k_scan_a<<<nb, 256, 0, stream>>>(cnt, bsum, dinv);
  k_scan_b<<<1, 512, 0, stream>>>(bsum, nb, off);
  k_scan_c<<<nb, 256, 0, stream>>>(cnt, bsum, off);
  k_fill<<<(EE + 255) / 256, 256, 0, stream>>>(row, col, off, cursor, csr);

  k_cvtw<<<(NF * NH + 255) / 256, 256, 0, stream>>>(W, Wt);

  k_gram<<<NH, NH, 0, stream>>>(W, B, M0, tr);
  float* Ms = M0;
  float* Md = M1;
  for (int s = 0; s < 8; s++) {
    k_sq<<<NH, NH, 0, stream>>>(Ms, Md, tr + s, tr + s + 1);
    float* tmp = Ms; Ms = Md; Md = tmp;
  }
  k_final<<<1, NH, 0, stream>>>(Ms, B, sig);

  k_mfma<<<(NN + 127) / 128, 256, 0, stream>>>(x, Wt, dinv, hs);
  k_gather<<<(NN + 3) / 4, 256, 0, stream>>>(hs, csr, off, dinv, b, pa, sig, out);
}

// Round 4
// 368.439 us; speedup vs baseline: 1.2840x; 1.0451x over previous
//
#include <hip/hip_runtime.h>

#define NN 100000
#define EE 1600000
#define NF 256
#define NH 128

typedef unsigned int u32;
typedef unsigned short u16;
typedef __attribute__((ext_vector_type(8))) short short8;
typedef __attribute__((ext_vector_type(4))) float f32x4;

static __device__ __forceinline__ u16 f2bf(float f) {
  u32 u = __float_as_uint(f);
  u32 r = (u + 0x7FFFu + ((u >> 16) & 1u)) >> 16;
  return (u16)r;
}
static __device__ __forceinline__ float bflo(u32 u) { return __uint_as_float(u << 16); }
static __device__ __forceinline__ float bfhi(u32 u) { return __uint_as_float(u & 0xFFFF0000u); }

// ---------------- degree count ----------------
__global__ void k_count(const int* __restrict__ col, u32* __restrict__ cnt) {
  int e = blockIdx.x * blockDim.x + threadIdx.x;
  if (e < EE) {
    u32 d = (u32)col[e];
    if (d < NN) atomicAdd(&cnt[d], 1u);
  }
}

// ---------------- scan (3-pass) + fused dinv ----------------
__global__ void k_scan_a(const u32* __restrict__ cnt, u32* __restrict__ bsum,
                         float* __restrict__ dinv) {
  __shared__ u32 s[256];
  int t = threadIdx.x;
  int i = blockIdx.x * 256 + t;
  u32 v = (i < NN) ? cnt[i] : 0u;
  if (i < NN) dinv[i] = rsqrtf((float)(v + 1u));  // +1 self-loop
  s[t] = v;
  __syncthreads();
  for (int d = 128; d > 0; d >>= 1) { if (t < d) s[t] += s[t + d]; __syncthreads(); }
  if (t == 0) bsum[blockIdx.x] = s[0];
}

__global__ void k_scan_b(u32* __restrict__ bsum, int nb, u32* __restrict__ off) {
  __shared__ u32 a[512];
  int t = threadIdx.x;
  u32 v = (t < nb) ? bsum[t] : 0u;
  a[t] = v;
  __syncthreads();
  for (int d = 1; d < 512; d <<= 1) {
    u32 x = a[t];
    if (t >= d) x += a[t - d];
    __syncthreads();
    a[t] = x;
    __syncthreads();
  }
  if (t < nb) bsum[t] = a[t] - v;
  if (t == 0) off[NN] = EE;
}

__global__ void k_scan_c(const u32* __restrict__ cnt, const u32* __restrict__ bbase,
                         u32* __restrict__ off) {
  __shared__ u32 a[256];
  int t = threadIdx.x;
  int i = blockIdx.x * 256 + t;
  u32 v = (i < NN) ? cnt[i] : 0u;
  a[t] = v;
  __syncthreads();
  for (int d = 1; d < 256; d <<= 1) {
    u32 x = a[t];
    if (t >= d) x += a[t - d];
    __syncthreads();
    a[t] = x;
    __syncthreads();
  }
  if (i < NN) off[i] = bbase[blockIdx.x] + a[t] - v;
}

// ---------------- CSR fill: XCD-pinned dst-ranges ----------------
// Block b: dst-range r = b&7 (12500 nodes), edge-slice j = b>>3.
// All csr writes for range r come from blocks on XCD r (round-robin dispatch)
// -> that XCD's L2 write-combines the random 4B stores (writeback ~6.4MB,
// not 1.6M x 64B). Edges re-read 8x but slice-consecutive blocks share L3.
#define FRB 128  // slices; EE/FRB = 12500 exactly
__global__ __launch_bounds__(256) void k_fill(const int* __restrict__ row,
                                              const int* __restrict__ col,
                                              const u32* __restrict__ off,
                                              u32* __restrict__ cursor,
                                              int* __restrict__ csr) {
  int r = blockIdx.x & 7;
  int j = blockIdx.x >> 3;
  int lo = r * (NN / 8), hi = lo + (NN / 8);
  int e0 = j * (EE / FRB);
  int e1 = e0 + (EE / FRB);
  for (int e = e0 + threadIdx.x; e < e1; e += 256) {
    int d = col[e];
    if (d >= lo && d < hi) {
      u32 pos = off[d] + atomicAdd(&cursor[d], 1u);
      csr[pos] = row[e];
    }
  }
}

// ---------------- W transpose + bf16 convert: Wt[c][k] ----------------
__global__ void k_cvtw(const float* __restrict__ W, u16* __restrict__ Wt) {
  int idx = blockIdx.x * 256 + threadIdx.x;
  if (idx < NF * NH) {
    int c = idx >> 8;   // 0..127
    int k = idx & 255;  // 0..255
    Wt[idx] = f2bf(W[k * NH + c]);
  }
}

// ---------------- spectral norm chain (validated R1/R2) ----------------
__global__ void k_gram(const float* __restrict__ W, float* __restrict__ B,
                       float* __restrict__ M0, float* __restrict__ tr) {
  __shared__ float wi[NF];
  int i = blockIdx.x, j = threadIdx.x;
  for (int k = j; k < NF; k += NH) wi[k] = W[k * NH + i];
  __syncthreads();
  float acc = 0.f;
  for (int k = 0; k < NF; k++) acc += wi[k] * W[k * NH + j];
  B[i * NH + j] = acc;
  M0[i * NH + j] = acc;
  if (i == j) atomicAdd(tr, acc);
}

__global__ void k_sq(const float* __restrict__ Min, float* __restrict__ Mout,
                     const float* __restrict__ tr_in, float* __restrict__ tr_out) {
  __shared__ float ri[NH];
  int i = blockIdx.x, j = threadIdx.x;
  ri[j] = Min[i * NH + j];
  __syncthreads();
  float acc = 0.f;
  for (int k = 0; k < NH; k++) acc += ri[k] * Min[k * NH + j];
  float it = 1.0f / tr_in[0];
  acc *= it * it;
  Mout[i * NH + j] = acc;
  if (i == j) atomicAdd(tr_out, acc);
}

__global__ void k_final(const float* __restrict__ M, const float* __restrict__ B,
                        float* __restrict__ sig) {
  __shared__ float u[NH], red[NH];
  __shared__ int idx[NH];
  int t = threadIdx.x;
  red[t] = M[t * NH + t];
  idx[t] = t;
  __syncthreads();
  for (int d = 64; d > 0; d >>= 1) {
    if (t < d && red[t + d] > red[t]) { red[t] = red[t + d]; idx[t] = idx[t + d]; }
    __syncthreads();
  }
  int jm = idx[0];
  __syncthreads();
  u[t] = M[t * NH + jm];
  __syncthreads();
  float acc = 0.f;
  for (int k = 0; k < NH; k++) acc += B[t * NH + k] * u[k];
  red[t] = u[t] * acc;
  __syncthreads();
  for (int d = 64; d > 0; d >>= 1) { if (t < d) red[t] += red[t + d]; __syncthreads(); }
  float numer = red[0];
  __syncthreads();
  red[t] = u[t] * u[t];
  __syncthreads();
  for (int d = 64; d > 0; d >>= 1) { if (t < d) red[t] += red[t + d]; __syncthreads(); }
  float denom = red[0];
  if (t == 0) sig[0] = rsqrtf(numer / denom);  // 1/sigma
}

// ---------------- MFMA GEMM: hs_bf16[n] = bf16(dinv[n] * (x[n] @ W)) -------
__global__ __launch_bounds__(256) void k_mfma(const float* __restrict__ x,
                                              const u16* __restrict__ Wt,
                                              const float* __restrict__ dinv,
                                              u16* __restrict__ hs) {
  __shared__ __align__(16) char As[128 * 128];
  __shared__ __align__(16) char Bs[128 * 128];
  int t = threadIdx.x;
  int l = t & 63, w = t >> 6;
  int row0 = blockIdx.x * 128;

  int ar = t >> 1;
  int ah = t & 1;
  long agr = (long)((row0 + ar < NN) ? (row0 + ar) : (NN - 1)) * NF;
  int bc = t >> 1;
  int bh = t & 1;

  f32x4 acc[2][8] = {};

  for (int ks = 0; ks < 4; ks++) {
    int k0 = ks * 64;
    float4 av[8];
    uint4 bv[4];
#pragma unroll
    for (int i = 0; i < 8; i++) av[i] = *(const float4*)&x[agr + k0 + ah * 32 + i * 4];
#pragma unroll
    for (int i = 0; i < 4; i++) bv[i] = *(const uint4*)&Wt[bc * 256 + k0 + (bh * 4 + i) * 8];
    __syncthreads();
#pragma unroll
    for (int q = 0; q < 4; q++) {
      const float* f = (const float*)&av[q * 2];
      u32 wd[4];
#pragma unroll
      for (int i2 = 0; i2 < 4; i2++)
        wd[i2] = (u32)f2bf(f[2 * i2]) | ((u32)f2bf(f[2 * i2 + 1]) << 16);
      int inner = (ah * 64 + q * 16) ^ ((ar & 7) << 4);
      *(uint4*)(As + ar * 128 + inner) = *(uint4*)wd;
    }
#pragma unroll
    for (int i = 0; i < 4; i++) {
      int inner = ((bh * 4 + i) * 16) ^ ((bc & 7) << 4);
      *(uint4*)(Bs + bc * 128 + inner) = bv[i];
    }
    __syncthreads();
#pragma unroll
    for (int ksub = 0; ksub < 2; ksub++) {
      int kin = ksub * 64 + (l >> 4) * 16;
      short8 af[2], bf[8];
#pragma unroll
      for (int m = 0; m < 2; m++) {
        int r = w * 32 + m * 16 + (l & 15);
        af[m] = *(const short8*)(As + r * 128 + (kin ^ ((r & 7) << 4)));
      }
#pragma unroll
      for (int n = 0; n < 8; n++) {
        int c = n * 16 + (l & 15);
        bf[n] = *(const short8*)(Bs + c * 128 + (kin ^ ((c & 7) << 4)));
      }
#pragma unroll
      for (int m = 0; m < 2; m++)
#pragma unroll
        for (int n = 0; n < 8; n++)
          acc[m][n] = __builtin_amdgcn_mfma_f32_16x16x32_bf16(af[m], bf[n], acc[m][n], 0, 0, 0);
    }
  }
#pragma unroll
  for (int m = 0; m < 2; m++) {
    int rb = row0 + w * 32 + m * 16 + (l >> 4) * 4;
    float dv[4];
#pragma unroll
    for (int g = 0; g < 4; g++) dv[g] = (rb + g < NN) ? dinv[rb + g] : 0.f;
#pragma unroll
    for (int n = 0; n < 8; n++) {
      int c = n * 16 + (l & 15);
#pragma unroll
      for (int g = 0; g < 4; g++) {
        int r = rb + g;
        if (r < NN) hs[(size_t)r * NH + c] = f2bf(acc[m][n][g] * dv[g]);
      }
    }
  }
}

// ---------------- gather + epilogue (wave per node, bf16 rows) ----------------
__global__ __launch_bounds__(256) void k_gather(const u16* __restrict__ hs,
                                                const int* __restrict__ csr,
                                                const u32* __restrict__ off,
                                                const float* __restrict__ dinv,
                                                const float* __restrict__ b,
                                                const float* __restrict__ pa,
                                                const float* __restrict__ sig,
                                                float* __restrict__ out) {
  int wid = threadIdx.x >> 6;
  int lane = threadIdx.x & 63;
  int n = blockIdx.x * 4 + wid;
  if (n >= NN) return;
  u32 s0 = off[n], s1 = off[n + 1];
  const u32* hrow = (const u32*)hs;  // 2 bf16 per u32; row stride 64 u32
  float ax, ay;
  {
    u32 u = hrow[(size_t)n * 64 + lane];  // self-loop term
    ax = bflo(u); ay = bfhi(u);
  }
  u32 e = s0;
  for (; e + 4 <= s1; e += 4) {
    int i0 = csr[e], i1 = csr[e + 1], i2 = csr[e + 2], i3 = csr[e + 3];
    u32 u0 = hrow[(size_t)i0 * 64 + lane];
    u32 u1 = hrow[(size_t)i1 * 64 + lane];
    u32 u2 = hrow[(size_t)i2 * 64 + lane];
    u32 u3 = hrow[(size_t)i3 * 64 + lane];
    ax += bflo(u0) + bflo(u1) + bflo(u2) + bflo(u3);
    ay += bfhi(u0) + bfhi(u1) + bfhi(u2) + bfhi(u3);
  }
  for (; e < s1; e++) {
    u32 u = hrow[(size_t)csr[e] * 64 + lane];
    ax += bflo(u); ay += bfhi(u);
  }
  float dv = dinv[n] * sig[0];
  float2 bb = *(const float2*)&b[lane * 2];
  float a = pa[0];
  float v0 = ax * dv + bb.x;
  float v1 = ay * dv + bb.y;
  float2 o;
  o.x = v0 > 0.f ? v0 : a * v0;
  o.y = v1 > 0.f ? v1 : a * v1;
  *(float2*)&out[(size_t)n * NH + lane * 2] = o;
}

// ---------------- launch ----------------
extern "C" void kernel_launch(void* const* d_in, const int* in_sizes, int n_in,
                              void* d_out, int out_size, void* d_ws, size_t ws_size,
                              hipStream_t stream) {
  const float* x = (const float*)d_in[0];
  const int* ei = (const int*)d_in[1];
  const float* W = (const float*)d_in[2];
  const float* b = (const float*)d_in[3];
  const float* pa = (const float*)d_in[4];
  float* out = (float*)d_out;
  const int* row = ei;        // sources
  const int* col = ei + EE;   // destinations

  char* base = (char*)d_ws;
  size_t o = 0;
  auto alloc = [&](size_t bytes) -> void* {
    void* p = base + o;
    o += (bytes + 63) & ~(size_t)63;
    return p;
  };
  u32* cnt = (u32*)alloc((size_t)NN * 4);
  u32* cursor = (u32*)alloc((size_t)NN * 4);
  float* tr = (float*)alloc(16 * 4);
  float* sig = (float*)alloc(64);
  // --- everything above zeroed each call ---
  size_t zbytes = o;
  float* dinv = (float*)alloc((size_t)NN * 4);
  u32* off = (u32*)alloc((size_t)(NN + 4) * 4);
  u32* bsum = (u32*)alloc(512 * 4);
  int* csr = (int*)alloc((size_t)EE * 4);
  float* B = (float*)alloc((size_t)NH * NH * 4);
  float* M0 = (float*)alloc((size_t)NH * NH * 4);
  float* M1 = (float*)alloc((size_t)NH * NH * 4);
  u16* Wt = (u16*)alloc((size_t)NF * NH * 2);
  u16* hs = (u16*)alloc((size_t)NN * NH * 2);
  (void)ws_size; (void)in_sizes; (void)n_in; (void)out_size;

  hipMemsetAsync(cnt, 0, zbytes, stream);

  k_count<<<(EE + 255) / 256, 256, 0, stream>>>(col, cnt);

  int nb = (NN + 255) / 256;  // 391
  k_scan_a<<<nb, 256, 0, stream>>>(cnt, bsum, dinv);
  k_scan_b<<<1, 512, 0, stream>>>(bsum, nb, off);
  k_scan_c<<<nb, 256, 0, stream>>>(cnt, bsum, off);
  k_fill<<<FRB * 8, 256, 0, stream>>>(row, col, off, cursor, csr);

  k_cvtw<<<(NF * NH + 255) / 256, 256, 0, stream>>>(W, Wt);

  k_gram<<<NH, NH, 0, stream>>>(W, B, M0, tr);
  float* Ms = M0;
  float* Md = M1;
  for (int s = 0; s < 8; s++) {
    k_sq<<<NH, NH, 0, stream>>>(Ms, Md, tr + s, tr + s + 1);
    float* tmp = Ms; Ms = Md; Md = tmp;
  }
  k_final<<<1, NH, 0, stream>>>(Ms, B, sig);

  k_mfma<<<(NN + 127) / 128, 256, 0, stream>>>(x, Wt, dinv, hs);
  k_gather<<<(NN + 3) / 4, 256, 0, stream>>>(hs, csr, off, dinv, b, pa, sig, out);
}

// Round 5
// 256.242 us; speedup vs baseline: 1.8462x; 1.4379x over previous
//
#include <hip/hip_runtime.h>

#define NN 100000
#define EE 1600000
#define NF 256
#define NH 128

#define BK 98        // buckets of 1024 nodes: ceil(100000/1024)
#define BNODE 1024
#define CHUNK 4096
#define NCHUNK ((EE + CHUNK - 1) / CHUNK)  // 391
#define CAP 24576    // P2 LDS staging capacity (mean 16327, std ~128)

typedef unsigned int u32;
typedef unsigned short u16;
typedef __attribute__((ext_vector_type(8))) short short8;
typedef __attribute__((ext_vector_type(4))) float f32x4;

static __device__ __forceinline__ u16 f2bf(float f) {
  u32 u = __float_as_uint(f);
  u32 r = (u + 0x7FFFu + ((u >> 16) & 1u)) >> 16;
  return (u16)r;
}
static __device__ __forceinline__ float bflo(u32 u) { return __uint_as_float(u << 16); }
static __device__ __forceinline__ float bfhi(u32 u) { return __uint_as_float(u & 0xFFFF0000u); }

// ---------------- P0: bucket histogram ----------------
__global__ __launch_bounds__(256) void k_p0(const int* __restrict__ col,
                                            u32* __restrict__ bcnt) {
  __shared__ u32 hist[BK];
  int t = threadIdx.x;
  if (t < BK) hist[t] = 0;
  __syncthreads();
  int e0 = blockIdx.x * CHUNK;
  int e1 = min(e0 + CHUNK, EE);
  for (int e = e0 + t; e < e1; e += 256) {
    u32 d = (u32)col[e];
    atomicAdd(&hist[d >> 10], 1u);
  }
  __syncthreads();
  if (t < BK && hist[t]) atomicAdd(&bcnt[t], hist[t]);
}

// ---------------- bucket scan (tiny) ----------------
__global__ void k_bscan(const u32* __restrict__ bcnt, u32* __restrict__ bbase,
                        u32* __restrict__ gcur, u32* __restrict__ off) {
  if (threadIdx.x == 0) {
    u32 s = 0;
    for (int b = 0; b < BK; b++) { bbase[b] = s; gcur[b] = s; s += bcnt[b]; }
    off[NN] = EE;
  }
}

// ---------------- P1: counting-sort edges into buckets (run-writes) --------
__global__ __launch_bounds__(256) void k_p1(const int* __restrict__ row,
                                            const int* __restrict__ col,
                                            u32* __restrict__ gcur,
                                            u32* __restrict__ binned) {
  __shared__ u32 keybuf[CHUNK];
  __shared__ unsigned char bktbuf[CHUNK];
  __shared__ u32 hist[BK], lstart[BK], lofs[BK], gb[BK];
  int t = threadIdx.x;
  if (t < BK) hist[t] = 0;
  __syncthreads();
  int e0 = blockIdx.x * CHUNK;
  int n = min(CHUNK, EE - e0);
  for (int i = t; i < n; i += 256) {
    u32 d = (u32)col[e0 + i];
    atomicAdd(&hist[d >> 10], 1u);
  }
  __syncthreads();
  if (t == 0) {
    u32 s = 0;
    for (int b = 0; b < BK; b++) { lstart[b] = s; lofs[b] = s; s += hist[b]; }
  }
  __syncthreads();
  if (t < BK && hist[t]) gb[t] = atomicAdd(&gcur[t], hist[t]);
  __syncthreads();
  for (int i = t; i < n; i += 256) {
    u32 d = (u32)col[e0 + i];
    u32 s = (u32)row[e0 + i];
    u32 b = d >> 10;
    u32 p = atomicAdd(&lofs[b], 1u);
    keybuf[p] = ((d & 1023u) << 17) | s;
    bktbuf[p] = (unsigned char)b;
  }
  __syncthreads();
  for (int i = t; i < n; i += 256) {
    u32 b = bktbuf[i];
    binned[gb[b] + ((u32)i - lstart[b])] = keybuf[i];
  }
}

// ---------------- P2: per-bucket counting sort in LDS ----------------
// Produces off[], dinv[], csr[] with purely sequential global writes.
__global__ __launch_bounds__(1024) void k_p2(const u32* __restrict__ binned,
                                             const u32* __restrict__ bbase,
                                             const u32* __restrict__ bcnt,
                                             u32* __restrict__ off,
                                             float* __restrict__ dinv,
                                             int* __restrict__ csr) {
  __shared__ u32 hist[BNODE];
  __shared__ u32 loff[BNODE];
  __shared__ u32 cur[BNODE];
  __shared__ u32 stage[CAP];
  int b = blockIdx.x, t = threadIdx.x;
  u32 base = bbase[b], cnt = bcnt[b];
  hist[t] = 0;
  __syncthreads();
  for (u32 i = t; i < cnt; i += BNODE) {
    u32 key = binned[base + i];
    atomicAdd(&hist[key >> 17], 1u);
  }
  __syncthreads();
  u32 v = hist[t];
  loff[t] = v;
  __syncthreads();
  for (int d = 1; d < BNODE; d <<= 1) {  // inclusive Hillis-Steele
    u32 x = loff[t];
    u32 y = (t >= d) ? loff[t - d] : 0u;
    __syncthreads();
    loff[t] = x + y;
    __syncthreads();
  }
  u32 ex = loff[t] - v;  // exclusive prefix
  cur[t] = ex;
  int g = b * BNODE + t;
  if (g < NN) {
    off[g] = base + ex;
    dinv[g] = rsqrtf((float)(v + 1u));
  }
  __syncthreads();
  if (cnt <= CAP) {
    for (u32 i = t; i < cnt; i += BNODE) {
      u32 key = binned[base + i];
      u32 p = atomicAdd(&cur[key >> 17], 1u);
      stage[p] = key & 0x1FFFFu;
    }
    __syncthreads();
    for (u32 i = t; i < cnt; i += BNODE) csr[base + i] = (int)stage[i];
  } else {  // statistically unreachable fallback, correctness-preserving
    for (u32 i = t; i < cnt; i += BNODE) {
      u32 key = binned[base + i];
      u32 p = atomicAdd(&cur[key >> 17], 1u);
      csr[base + p] = (int)(key & 0x1FFFFu);
    }
  }
}

// ---------------- W transpose + bf16 convert: Wt[c][k] ----------------
__global__ void k_cvtw(const float* __restrict__ W, u16* __restrict__ Wt) {
  int idx = blockIdx.x * 256 + threadIdx.x;
  if (idx < NF * NH) {
    int c = idx >> 8;
    int k = idx & 255;
    Wt[idx] = f2bf(W[k * NH + c]);
  }
}

// ---------------- spectral norm chain (validated R1-R4) ----------------
__global__ void k_gram(const float* __restrict__ W, float* __restrict__ B,
                       float* __restrict__ M0, float* __restrict__ tr) {
  __shared__ float wi[NF];
  int i = blockIdx.x, j = threadIdx.x;
  for (int k = j; k < NF; k += NH) wi[k] = W[k * NH + i];
  __syncthreads();
  float acc = 0.f;
  for (int k = 0; k < NF; k++) acc += wi[k] * W[k * NH + j];
  B[i * NH + j] = acc;
  M0[i * NH + j] = acc;
  if (i == j) atomicAdd(tr, acc);
}

__global__ void k_sq(const float* __restrict__ Min, float* __restrict__ Mout,
                     const float* __restrict__ tr_in, float* __restrict__ tr_out) {
  __shared__ float ri[NH];
  int i = blockIdx.x, j = threadIdx.x;
  ri[j] = Min[i * NH + j];
  __syncthreads();
  float acc = 0.f;
  for (int k = 0; k < NH; k++) acc += ri[k] * Min[k * NH + j];
  float it = 1.0f / tr_in[0];
  acc *= it * it;
  Mout[i * NH + j] = acc;
  if (i == j) atomicAdd(tr_out, acc);
}

__global__ void k_final(const float* __restrict__ M, const float* __restrict__ B,
                        float* __restrict__ sig) {
  __shared__ float u[NH], red[NH];
  __shared__ int idx[NH];
  int t = threadIdx.x;
  red[t] = M[t * NH + t];
  idx[t] = t;
  __syncthreads();
  for (int d = 64; d > 0; d >>= 1) {
    if (t < d && red[t + d] > red[t]) { red[t] = red[t + d]; idx[t] = idx[t + d]; }
    __syncthreads();
  }
  int jm = idx[0];
  __syncthreads();
  u[t] = M[t * NH + jm];
  __syncthreads();
  float acc = 0.f;
  for (int k = 0; k < NH; k++) acc += B[t * NH + k] * u[k];
  red[t] = u[t] * acc;
  __syncthreads();
  for (int d = 64; d > 0; d >>= 1) { if (t < d) red[t] += red[t + d]; __syncthreads(); }
  float numer = red[0];
  __syncthreads();
  red[t] = u[t] * u[t];
  __syncthreads();
  for (int d = 64; d > 0; d >>= 1) { if (t < d) red[t] += red[t + d]; __syncthreads(); }
  float denom = red[0];
  if (t == 0) sig[0] = rsqrtf(numer / denom);  // 1/sigma
}

// ---------------- MFMA GEMM: hs_bf16[n] = bf16(dinv[n] * (x[n] @ W)) -------
__global__ __launch_bounds__(256) void k_mfma(const float* __restrict__ x,
                                              const u16* __restrict__ Wt,
                                              const float* __restrict__ dinv,
                                              u16* __restrict__ hs) {
  __shared__ __align__(16) char As[128 * 128];
  __shared__ __align__(16) char Bs[128 * 128];
  int t = threadIdx.x;
  int l = t & 63, w = t >> 6;
  int row0 = blockIdx.x * 128;

  int ar = t >> 1;
  int ah = t & 1;
  long agr = (long)((row0 + ar < NN) ? (row0 + ar) : (NN - 1)) * NF;
  int bc = t >> 1;
  int bh = t & 1;

  f32x4 acc[2][8] = {};

  for (int ks = 0; ks < 4; ks++) {
    int k0 = ks * 64;
    float4 av[8];
    uint4 bv[4];
#pragma unroll
    for (int i = 0; i < 8; i++) av[i] = *(const float4*)&x[agr + k0 + ah * 32 + i * 4];
#pragma unroll
    for (int i = 0; i < 4; i++) bv[i] = *(const uint4*)&Wt[bc * 256 + k0 + (bh * 4 + i) * 8];
    __syncthreads();
#pragma unroll
    for (int q = 0; q < 4; q++) {
      const float* f = (const float*)&av[q * 2];
      u32 wd[4];
#pragma unroll
      for (int i2 = 0; i2 < 4; i2++)
        wd[i2] = (u32)f2bf(f[2 * i2]) | ((u32)f2bf(f[2 * i2 + 1]) << 16);
      int inner = (ah * 64 + q * 16) ^ ((ar & 7) << 4);
      *(uint4*)(As + ar * 128 + inner) = *(uint4*)wd;
    }
#pragma unroll
    for (int i = 0; i < 4; i++) {
      int inner = ((bh * 4 + i) * 16) ^ ((bc & 7) << 4);
      *(uint4*)(Bs + bc * 128 + inner) = bv[i];
    }
    __syncthreads();
#pragma unroll
    for (int ksub = 0; ksub < 2; ksub++) {
      int kin = ksub * 64 + (l >> 4) * 16;
      short8 af[2], bf[8];
#pragma unroll
      for (int m = 0; m < 2; m++) {
        int r = w * 32 + m * 16 + (l & 15);
        af[m] = *(const short8*)(As + r * 128 + (kin ^ ((r & 7) << 4)));
      }
#pragma unroll
      for (int n = 0; n < 8; n++) {
        int c = n * 16 + (l & 15);
        bf[n] = *(const short8*)(Bs + c * 128 + (kin ^ ((c & 7) << 4)));
      }
#pragma unroll
      for (int m = 0; m < 2; m++)
#pragma unroll
        for (int n = 0; n < 8; n++)
          acc[m][n] = __builtin_amdgcn_mfma_f32_16x16x32_bf16(af[m], bf[n], acc[m][n], 0, 0, 0);
    }
  }
#pragma unroll
  for (int m = 0; m < 2; m++) {
    int rb = row0 + w * 32 + m * 16 + (l >> 4) * 4;
    float dv[4];
#pragma unroll
    for (int g = 0; g < 4; g++) dv[g] = (rb + g < NN) ? dinv[rb + g] : 0.f;
#pragma unroll
    for (int n = 0; n < 8; n++) {
      int c = n * 16 + (l & 15);
#pragma unroll
      for (int g = 0; g < 4; g++) {
        int r = rb + g;
        if (r < NN) hs[(size_t)r * NH + c] = f2bf(acc[m][n][g] * dv[g]);
      }
    }
  }
}

// ---------------- gather + epilogue (wave per node, bf16 rows) ----------------
__global__ __launch_bounds__(256) void k_gather(const u16* __restrict__ hs,
                                                const int* __restrict__ csr,
                                                const u32* __restrict__ off,
                                                const float* __restrict__ dinv,
                                                const float* __restrict__ b,
                                                const float* __restrict__ pa,
                                                const float* __restrict__ sig,
                                                float* __restrict__ out) {
  int wid = threadIdx.x >> 6;
  int lane = threadIdx.x & 63;
  int n = blockIdx.x * 4 + wid;
  if (n >= NN) return;
  u32 s0 = off[n], s1 = off[n + 1];
  const u32* hrow = (const u32*)hs;  // 2 bf16 per u32; row stride 64 u32
  float ax, ay;
  {
    u32 u = hrow[(size_t)n * 64 + lane];  // self-loop term
    ax = bflo(u); ay = bfhi(u);
  }
  u32 e = s0;
  for (; e + 4 <= s1; e += 4) {
    int i0 = csr[e], i1 = csr[e + 1], i2 = csr[e + 2], i3 = csr[e + 3];
    u32 u0 = hrow[(size_t)i0 * 64 + lane];
    u32 u1 = hrow[(size_t)i1 * 64 + lane];
    u32 u2 = hrow[(size_t)i2 * 64 + lane];
    u32 u3 = hrow[(size_t)i3 * 64 + lane];
    ax += bflo(u0) + bflo(u1) + bflo(u2) + bflo(u3);
    ay += bfhi(u0) + bfhi(u1) + bfhi(u2) + bfhi(u3);
  }
  for (; e < s1; e++) {
    u32 u = hrow[(size_t)csr[e] * 64 + lane];
    ax += bflo(u); ay += bfhi(u);
  }
  float dv = dinv[n] * sig[0];
  float2 bb = *(const float2*)&b[lane * 2];
  float a = pa[0];
  float v0 = ax * dv + bb.x;
  float v1 = ay * dv + bb.y;
  float2 o;
  o.x = v0 > 0.f ? v0 : a * v0;
  o.y = v1 > 0.f ? v1 : a * v1;
  *(float2*)&out[(size_t)n * NH + lane * 2] = o;
}

// ---------------- launch ----------------
extern "C" void kernel_launch(void* const* d_in, const int* in_sizes, int n_in,
                              void* d_out, int out_size, void* d_ws, size_t ws_size,
                              hipStream_t stream) {
  const float* x = (const float*)d_in[0];
  const int* ei = (const int*)d_in[1];
  const float* W = (const float*)d_in[2];
  const float* b = (const float*)d_in[3];
  const float* pa = (const float*)d_in[4];
  float* out = (float*)d_out;
  const int* row = ei;        // sources
  const int* col = ei + EE;   // destinations

  char* base = (char*)d_ws;
  size_t o = 0;
  auto alloc = [&](size_t bytes) -> void* {
    void* p = base + o;
    o += (bytes + 63) & ~(size_t)63;
    return p;
  };
  // --- zeroed region ---
  u32* bcnt = (u32*)alloc(BK * 4);
  float* tr = (float*)alloc(16 * 4);
  float* sig = (float*)alloc(64);
  size_t zbytes = o;
  // --- rest ---
  u32* bbase = (u32*)alloc(BK * 4);
  u32* gcur = (u32*)alloc(BK * 4);
  float* dinv = (float*)alloc((size_t)NN * 4);
  u32* off = (u32*)alloc((size_t)(NN + 4) * 4);
  u32* binned = (u32*)alloc((size_t)EE * 4);
  int* csr = (int*)alloc((size_t)EE * 4);
  float* B = (float*)alloc((size_t)NH * NH * 4);
  float* M0 = (float*)alloc((size_t)NH * NH * 4);
  float* M1 = (float*)alloc((size_t)NH * NH * 4);
  u16* Wt = (u16*)alloc((size_t)NF * NH * 2);
  u16* hs = (u16*)alloc((size_t)NN * NH * 2);
  (void)ws_size; (void)in_sizes; (void)n_in; (void)out_size;

  hipMemsetAsync(bcnt, 0, zbytes, stream);

  k_p0<<<NCHUNK, 256, 0, stream>>>(col, bcnt);
  k_bscan<<<1, 64, 0, stream>>>(bcnt, bbase, gcur, off);
  k_p1<<<NCHUNK, 256, 0, stream>>>(row, col, gcur, binned);
  k_p2<<<BK, BNODE, 0, stream>>>(binned, bbase, bcnt, off, dinv, csr);

  k_cvtw<<<(NF * NH + 255) / 256, 256, 0, stream>>>(W, Wt);

  k_gram<<<NH, NH, 0, stream>>>(W, B, M0, tr);
  float* Ms = M0;
  float* Md = M1;
  for (int s = 0; s < 8; s++) {
    k_sq<<<NH, NH, 0, stream>>>(Ms, Md, tr + s, tr + s + 1);
    float* tmp = Ms; Ms = Md; Md = tmp;
  }
  k_final<<<1, NH, 0, stream>>>(Ms, B, sig);

  k_mfma<<<(NN + 127) / 128, 256, 0, stream>>>(x, Wt, dinv, hs);
  k_gather<<<(NN + 3) / 4, 256, 0, stream>>>(hs, csr, off, dinv, b, pa, sig, out);
}

// Round 6
// 242.770 us; speedup vs baseline: 1.9486x; 1.0555x over previous
//
#include <hip/hip_runtime.h>

#define NN 100000
#define EE 1600000
#define NF 256
#define NH 128

#define BK 98        // buckets of 1024 nodes: ceil(100000/1024)
#define BNODE 1024
#define CHUNK 4096
#define NCHUNK ((EE + CHUNK - 1) / CHUNK)  // 391
#define CAP 24576    // P2 LDS staging capacity (mean 16327, std ~128)

typedef unsigned int u32;
typedef unsigned short u16;
typedef __attribute__((ext_vector_type(8))) short short8;
typedef __attribute__((ext_vector_type(4))) float f32x4;

static __device__ __forceinline__ u16 f2bf(float f) {
  u32 u = __float_as_uint(f);
  u32 r = (u + 0x7FFFu + ((u >> 16) & 1u)) >> 16;
  return (u16)r;
}
static __device__ __forceinline__ float bflo(u32 u) { return __uint_as_float(u << 16); }
static __device__ __forceinline__ float bfhi(u32 u) { return __uint_as_float(u & 0xFFFF0000u); }

// ---------------- P0: bucket histogram ----------------
__global__ __launch_bounds__(256) void k_p0(const int* __restrict__ col,
                                            u32* __restrict__ bcnt) {
  __shared__ u32 hist[BK];
  int t = threadIdx.x;
  if (t < BK) hist[t] = 0;
  __syncthreads();
  int e0 = blockIdx.x * CHUNK;
  int e1 = min(e0 + CHUNK, EE);
  for (int e = e0 + t; e < e1; e += 256) {
    u32 d = (u32)col[e];
    atomicAdd(&hist[d >> 10], 1u);
  }
  __syncthreads();
  if (t < BK && hist[t]) atomicAdd(&bcnt[t], hist[t]);
}

// ---------------- bucket scan (tiny) ----------------
__global__ void k_bscan(const u32* __restrict__ bcnt, u32* __restrict__ bbase,
                        u32* __restrict__ gcur, u32* __restrict__ off) {
  if (threadIdx.x == 0) {
    u32 s = 0;
    for (int b = 0; b < BK; b++) { bbase[b] = s; gcur[b] = s; s += bcnt[b]; }
    off[NN] = EE;
  }
}

// ---------------- P1: counting-sort edges into buckets (run-writes) --------
__global__ __launch_bounds__(256) void k_p1(const int* __restrict__ row,
                                            const int* __restrict__ col,
                                            u32* __restrict__ gcur,
                                            u32* __restrict__ binned) {
  __shared__ u32 keybuf[CHUNK];
  __shared__ unsigned char bktbuf[CHUNK];
  __shared__ u32 hist[BK], lstart[BK], lofs[BK], gb[BK];
  int t = threadIdx.x;
  if (t < BK) hist[t] = 0;
  __syncthreads();
  int e0 = blockIdx.x * CHUNK;
  int n = min(CHUNK, EE - e0);
  for (int i = t; i < n; i += 256) {
    u32 d = (u32)col[e0 + i];
    atomicAdd(&hist[d >> 10], 1u);
  }
  __syncthreads();
  if (t == 0) {
    u32 s = 0;
    for (int b = 0; b < BK; b++) { lstart[b] = s; lofs[b] = s; s += hist[b]; }
  }
  __syncthreads();
  if (t < BK && hist[t]) gb[t] = atomicAdd(&gcur[t], hist[t]);
  __syncthreads();
  for (int i = t; i < n; i += 256) {
    u32 d = (u32)col[e0 + i];
    u32 s = (u32)row[e0 + i];
    u32 b = d >> 10;
    u32 p = atomicAdd(&lofs[b], 1u);
    keybuf[p] = ((d & 1023u) << 17) | s;
    bktbuf[p] = (unsigned char)b;
  }
  __syncthreads();
  for (int i = t; i < n; i += 256) {
    u32 b = bktbuf[i];
    binned[gb[b] + ((u32)i - lstart[b])] = keybuf[i];
  }
}

// ---------------- P2: per-bucket counting sort in LDS ----------------
__global__ __launch_bounds__(1024) void k_p2(const u32* __restrict__ binned,
                                             const u32* __restrict__ bbase,
                                             const u32* __restrict__ bcnt,
                                             u32* __restrict__ off,
                                             float* __restrict__ dinv,
                                             int* __restrict__ csr) {
  __shared__ u32 hist[BNODE];
  __shared__ u32 loff[BNODE];
  __shared__ u32 cur[BNODE];
  __shared__ u32 stage[CAP];
  int b = blockIdx.x, t = threadIdx.x;
  u32 base = bbase[b], cnt = bcnt[b];
  hist[t] = 0;
  __syncthreads();
  for (u32 i = t; i < cnt; i += BNODE) {
    u32 key = binned[base + i];
    atomicAdd(&hist[key >> 17], 1u);
  }
  __syncthreads();
  u32 v = hist[t];
  loff[t] = v;
  __syncthreads();
  for (int d = 1; d < BNODE; d <<= 1) {
    u32 x = loff[t];
    u32 y = (t >= d) ? loff[t - d] : 0u;
    __syncthreads();
    loff[t] = x + y;
    __syncthreads();
  }
  u32 ex = loff[t] - v;
  cur[t] = ex;
  int g = b * BNODE + t;
  if (g < NN) {
    off[g] = base + ex;
    dinv[g] = rsqrtf((float)(v + 1u));
  }
  __syncthreads();
  if (cnt <= CAP) {
    for (u32 i = t; i < cnt; i += BNODE) {
      u32 key = binned[base + i];
      u32 p = atomicAdd(&cur[key >> 17], 1u);
      stage[p] = key & 0x1FFFFu;
    }
    __syncthreads();
    for (u32 i = t; i < cnt; i += BNODE) csr[base + i] = (int)stage[i];
  } else {
    for (u32 i = t; i < cnt; i += BNODE) {
      u32 key = binned[base + i];
      u32 p = atomicAdd(&cur[key >> 17], 1u);
      csr[base + p] = (int)(key & 0x1FFFFu);
    }
  }
}

// ---------------- spectral norm chain + fused Wt transpose ----------------
__global__ void k_gram(const float* __restrict__ W, float* __restrict__ B,
                       float* __restrict__ M0, float* __restrict__ tr,
                       u16* __restrict__ Wt) {
  __shared__ float wi[NF];
  int i = blockIdx.x, j = threadIdx.x;
  for (int k = j; k < NF; k += NH) wi[k] = W[k * NH + i];
  __syncthreads();
  // fused cvtw: wi[] is column i of W = row i of Wt
  for (int k = j; k < NF; k += NH) Wt[i * NF + k] = f2bf(wi[k]);
  float acc = 0.f;
  for (int k = 0; k < NF; k++) acc += wi[k] * W[k * NH + j];
  B[i * NH + j] = acc;
  M0[i * NH + j] = acc;
  if (i == j) atomicAdd(tr, acc);
}

__global__ void k_sq(const float* __restrict__ Min, float* __restrict__ Mout,
                     const float* __restrict__ tr_in, float* __restrict__ tr_out) {
  __shared__ float ri[NH];
  int i = blockIdx.x, j = threadIdx.x;
  ri[j] = Min[i * NH + j];
  __syncthreads();
  float acc = 0.f;
  for (int k = 0; k < NH; k++) acc += ri[k] * Min[k * NH + j];
  float it = 1.0f / tr_in[0];
  acc *= it * it;
  Mout[i * NH + j] = acc;
  if (i == j) atomicAdd(tr_out, acc);
}

__global__ void k_final(const float* __restrict__ M, const float* __restrict__ B,
                        float* __restrict__ sig) {
  __shared__ float u[NH], red[NH];
  __shared__ int idx[NH];
  int t = threadIdx.x;
  red[t] = M[t * NH + t];
  idx[t] = t;
  __syncthreads();
  for (int d = 64; d > 0; d >>= 1) {
    if (t < d && red[t + d] > red[t]) { red[t] = red[t + d]; idx[t] = idx[t + d]; }
    __syncthreads();
  }
  int jm = idx[0];
  __syncthreads();
  u[t] = M[t * NH + jm];
  __syncthreads();
  float acc = 0.f;
  for (int k = 0; k < NH; k++) acc += B[t * NH + k] * u[k];
  red[t] = u[t] * acc;
  __syncthreads();
  for (int d = 64; d > 0; d >>= 1) { if (t < d) red[t] += red[t + d]; __syncthreads(); }
  float numer = red[0];
  __syncthreads();
  red[t] = u[t] * u[t];
  __syncthreads();
  for (int d = 64; d > 0; d >>= 1) { if (t < d) red[t] += red[t + d]; __syncthreads(); }
  float denom = red[0];
  if (t == 0) sig[0] = rsqrtf(numer / denom);  // 1/sigma
}

// ---------------- MFMA GEMM, barrier-free main loop ----------------
// Wave w owns rows row0+w*32 .. +31 (2 m-frags), all 128 cols (8 n-frags).
// A-frags read directly from x (f32->bf16 in-reg, prefetch 1 K-step ahead);
// B-frags read directly from Wt (64KB, L1/L2-hot). No __syncthreads in loop.
// Frag layout (ref-checked R3-R5): lane l: A[row=l&15][k=(l>>4)*8+0..7],
// B[col=l&15][k same]; C/D col=l&15, row=(l>>4)*4+reg.
__global__ __launch_bounds__(256) void k_mfma(const float* __restrict__ x,
                                              const u16* __restrict__ Wt,
                                              const float* __restrict__ dinv,
                                              u16* __restrict__ hs) {
  __shared__ __align__(16) u16 tile[128 * 128];  // 32KB epilogue repack
  int t = threadIdx.x;
  int l = t & 63, w = t >> 6;
  int row0 = blockIdx.x * 128;
  int lr = l & 15;
  int lk = (l >> 4) * 8;

  long arow[2];
#pragma unroll
  for (int m = 0; m < 2; m++) {
    int r = row0 + w * 32 + m * 16 + lr;
    arow[m] = (long)((r < NN) ? r : (NN - 1)) * NF;
  }

  f32x4 acc[2][8] = {};
  short8 afr[2][2];

#define LOADA(ph, k0)                                                        \
  {                                                                          \
    _Pragma("unroll") for (int m = 0; m < 2; m++) {                          \
      float4 p0 = *(const float4*)&x[arow[m] + (k0) + lk];                   \
      float4 p1 = *(const float4*)&x[arow[m] + (k0) + lk + 4];               \
      u32 wd[4];                                                             \
      wd[0] = (u32)f2bf(p0.x) | ((u32)f2bf(p0.y) << 16);                     \
      wd[1] = (u32)f2bf(p0.z) | ((u32)f2bf(p0.w) << 16);                     \
      wd[2] = (u32)f2bf(p1.x) | ((u32)f2bf(p1.y) << 16);                     \
      wd[3] = (u32)f2bf(p1.z) | ((u32)f2bf(p1.w) << 16);                     \
      afr[ph][m] = *(short8*)wd;                                             \
    }                                                                        \
  }

  LOADA(0, 0)
#pragma unroll
  for (int ks = 0; ks < 8; ks++) {
    int cur = ks & 1, nxt = cur ^ 1;
    if (ks < 7) LOADA(nxt, (ks + 1) * 32)
    short8 bfr[8];
#pragma unroll
    for (int n = 0; n < 8; n++)
      bfr[n] = *(const short8*)&Wt[(n * 16 + lr) * NF + ks * 32 + lk];
#pragma unroll
    for (int m = 0; m < 2; m++)
#pragma unroll
      for (int n = 0; n < 8; n++)
        acc[m][n] = __builtin_amdgcn_mfma_f32_16x16x32_bf16(afr[cur][m], bfr[n], acc[m][n], 0, 0, 0);
  }
#undef LOADA

  // epilogue: scale, cvt, repack via LDS, coalesced uint4 stores
#pragma unroll
  for (int m = 0; m < 2; m++) {
    int rbl = w * 32 + m * 16 + (l >> 4) * 4;  // local row base
    float dv[4];
#pragma unroll
    for (int g = 0; g < 4; g++) {
      int r = row0 + rbl + g;
      dv[g] = (r < NN) ? dinv[r] : 0.f;
    }
#pragma unroll
    for (int n = 0; n < 8; n++)
#pragma unroll
      for (int g = 0; g < 4; g++)
        tile[(rbl + g) * 128 + n * 16 + lr] = f2bf(acc[m][n][g] * dv[g]);
  }
  __syncthreads();
  const uint4* tl = (const uint4*)tile;
  size_t outb = (size_t)row0 * NH;
#pragma unroll
  for (int k = 0; k < 8; k++) {
    int u = t + k * 256;           // uint4 index; row = u>>4 (16 uint4/row)
    if (row0 + (u >> 4) < NN) *(uint4*)&hs[outb + (size_t)u * 8] = tl[u];
  }
}

// ---------------- gather + epilogue (wave per node, bf16 rows) ----------------
__global__ __launch_bounds__(256) void k_gather(const u16* __restrict__ hs,
                                                const int* __restrict__ csr,
                                                const u32* __restrict__ off,
                                                const float* __restrict__ dinv,
                                                const float* __restrict__ b,
                                                const float* __restrict__ pa,
                                                const float* __restrict__ sig,
                                                float* __restrict__ out) {
  int wid = threadIdx.x >> 6;
  int lane = threadIdx.x & 63;
  int n = blockIdx.x * 4 + wid;
  if (n >= NN) return;
  u32 s0 = off[n], s1 = off[n + 1];
  const u32* hrow = (const u32*)hs;
  float ax, ay;
  {
    u32 u = hrow[(size_t)n * 64 + lane];
    ax = bflo(u); ay = bfhi(u);
  }
  u32 e = s0;
  for (; e + 4 <= s1; e += 4) {
    int i0 = csr[e], i1 = csr[e + 1], i2 = csr[e + 2], i3 = csr[e + 3];
    u32 u0 = hrow[(size_t)i0 * 64 + lane];
    u32 u1 = hrow[(size_t)i1 * 64 + lane];
    u32 u2 = hrow[(size_t)i2 * 64 + lane];
    u32 u3 = hrow[(size_t)i3 * 64 + lane];
    ax += bflo(u0) + bflo(u1) + bflo(u2) + bflo(u3);
    ay += bfhi(u0) + bfhi(u1) + bfhi(u2) + bfhi(u3);
  }
  for (; e < s1; e++) {
    u32 u = hrow[(size_t)csr[e] * 64 + lane];
    ax += bflo(u); ay += bfhi(u);
  }
  float dv = dinv[n] * sig[0];
  float2 bb = *(const float2*)&b[lane * 2];
  float a = pa[0];
  float v0 = ax * dv + bb.x;
  float v1 = ay * dv + bb.y;
  float2 o;
  o.x = v0 > 0.f ? v0 : a * v0;
  o.y = v1 > 0.f ? v1 : a * v1;
  *(float2*)&out[(size_t)n * NH + lane * 2] = o;
}

// ---------------- launch ----------------
extern "C" void kernel_launch(void* const* d_in, const int* in_sizes, int n_in,
                              void* d_out, int out_size, void* d_ws, size_t ws_size,
                              hipStream_t stream) {
  const float* x = (const float*)d_in[0];
  const int* ei = (const int*)d_in[1];
  const float* W = (const float*)d_in[2];
  const float* b = (const float*)d_in[3];
  const float* pa = (const float*)d_in[4];
  float* out = (float*)d_out;
  const int* row = ei;
  const int* col = ei + EE;

  char* base = (char*)d_ws;
  size_t o = 0;
  auto alloc = [&](size_t bytes) -> void* {
    void* p = base + o;
    o += (bytes + 63) & ~(size_t)63;
    return p;
  };
  // --- zeroed region ---
  u32* bcnt = (u32*)alloc(BK * 4);
  float* tr = (float*)alloc(16 * 4);
  float* sig = (float*)alloc(64);
  size_t zbytes = o;
  // --- rest ---
  u32* bbase = (u32*)alloc(BK * 4);
  u32* gcur = (u32*)alloc(BK * 4);
  float* dinv = (float*)alloc((size_t)NN * 4);
  u32* off = (u32*)alloc((size_t)(NN + 4) * 4);
  u32* binned = (u32*)alloc((size_t)EE * 4);
  int* csr = (int*)alloc((size_t)EE * 4);
  float* B = (float*)alloc((size_t)NH * NH * 4);
  float* M0 = (float*)alloc((size_t)NH * NH * 4);
  float* M1 = (float*)alloc((size_t)NH * NH * 4);
  u16* Wt = (u16*)alloc((size_t)NF * NH * 2);
  u16* hs = (u16*)alloc((size_t)NN * NH * 2);
  (void)ws_size; (void)in_sizes; (void)n_in; (void)out_size;

  hipMemsetAsync(bcnt, 0, zbytes, stream);

  k_p0<<<NCHUNK, 256, 0, stream>>>(col, bcnt);
  k_bscan<<<1, 64, 0, stream>>>(bcnt, bbase, gcur, off);
  k_p1<<<NCHUNK, 256, 0, stream>>>(row, col, gcur, binned);
  k_p2<<<BK, BNODE, 0, stream>>>(binned, bbase, bcnt, off, dinv, csr);

  k_gram<<<NH, NH, 0, stream>>>(W, B, M0, tr, Wt);
  float* Ms = M0;
  float* Md = M1;
  for (int s = 0; s < 8; s++) {
    k_sq<<<NH, NH, 0, stream>>>(Ms, Md, tr + s, tr + s + 1);
    float* tmp = Ms; Ms = Md; Md = tmp;
  }
  k_final<<<1, NH, 0, stream>>>(Ms, B, sig);

  k_mfma<<<(NN + 127) / 128, 256, 0, stream>>>(x, Wt, dinv, hs);
  k_gather<<<(NN + 3) / 4, 256, 0, stream>>>(hs, csr, off, dinv, b, pa, sig, out);
}